// Round 19
// baseline (136.534 us; speedup 1.0000x reference)
//
#include <hip/hip_runtime.h>

#define TPB  64      // one wave per block; all barriers wave-local
#define RPW  64      // rows per block, one per lane
#define XDIM 99
#define NJ   26
#define OUTW 78
#define LSTR 49      // LDS row stride: compute reads bank (17l+c)%32 -> conflict-free
#define CHW  48      // staged floats per row per chunk

__device__ __forceinline__ float fast_rcp(float a)  { return __builtin_amdgcn_rcpf(a); }
__device__ __forceinline__ float fast_sqrt(float a) { return __builtin_amdgcn_sqrtf(a); }

__device__ __forceinline__ void rodrigues(float ax, float ay, float az, float* R) {
    const float EPS = 1.1920928955078125e-07f;   // np.finfo(np.float32).eps
    float t = fast_sqrt(ax*ax + ay*ay + az*az);
    float inv = fast_rcp(t + EPS);
    float r0 = ax*inv, r1 = ay*inv, r2 = az*inv;
    float s, c;
    __sincosf(t, &s, &c);
    float omc = 1.0f - c;
    float r00 = r0*r0, r11 = r1*r1, r22 = r2*r2;
    float r01 = r0*r1, r02 = r0*r2, r12 = r1*r2;
    R[0] = 1.0f - omc*(r11 + r22);
    R[1] = -s*r2 + omc*r01;
    R[2] =  s*r1 + omc*r02;
    R[3] =  s*r2 + omc*r01;
    R[4] = 1.0f - omc*(r00 + r22);
    R[5] = -s*r0 + omc*r12;
    R[6] = -s*r1 + omc*r02;
    R[7] =  s*r0 + omc*r12;
    R[8] = 1.0f - omc*(r00 + r11);
}

// (64,4): VGPR cap 128 (R13's identical live set measured 84). LDS 12544B ->
// 12 blocks/CU = 3 waves/SIMD — the first config with real SIMD-level overlap.
__global__ __launch_bounds__(TPB, 4) void skel_fk(const float* __restrict__ x,
                                                  const float* __restrict__ off,
                                                  float* __restrict__ out) {
    __shared__ __align__(16) float buf[RPW * LSTR];   // 12544 B (64*49 = 3136 floats)
    const int l = threadIdx.x;
    const int row0 = blockIdx.x * RPW;
    const float* xb = x + (long long)row0 * XDIM;

    // per-lane staging decomposition: m = l + 64u -> (r_u, c_u); 3 divisions TOTAL
    // (R16's failure was 49 per-iteration magic-divs; here addressing is add-only).
    int gb[3], lb[3];
    #pragma unroll
    for (int u = 0; u < 3; ++u) {
        const int m = l + 64 * u;                // < 192
        const int r = m / CHW;                   // 0..3
        const int c = m - CHW * r;
        gb[u] = XDIM * r + c;                    // global base within 4-row group
        lb[u] = LSTR * r + c;                    // LDS base within 4-row group
    }

    // slot tables (slot 0 = hip, slots 1..25 follow ORDER)
    constexpr int OFF_IDX[NJ] = {0,1,2,3,4,6,7,8,9,11,12,13,14,15,16,17,18,19,20,22,24,25,26,27,28,30};
    constexpr int PAR[NJ]     = {-1,0,1,2,3,0,5,6,7,0,9,10,11,12,10,14,15,16,17,17,10,20,21,22,23,23};

    float ang[NJ][9];   // compile-time indices -> registers (dead matrices reclaimed)
    float pp[NJ][3];    // live until pack (R13-proven ~84-reg total)

    const float* row = &buf[l * LSTR];           // this lane's staged 48-float view

    // ---- stage chunk A: buf[49r+c] = x[99r+c], 64 rows x 48 floats, coalesced ----
    #pragma unroll
    for (int g = 0; g < 16; ++g)                 // 4 rows per group
        #pragma unroll
        for (int u = 0; u < 3; ++u)
            buf[196 * g + lb[u]] = xb[396 * g + gb[u]];
    __syncthreads();                             // 1-wave: ds_writes visible

    // ---- compute slots 0..12 from chunk A (cols 0..47) ----
    {
        float R[9];
        rodrigues(row[3], row[4], row[5], R);
        #pragma unroll
        for (int q = 0; q < 9; ++q) ang[0][q] = R[q];
        pp[0][0] = off[0] + row[0];
        pp[0][1] = off[1] + row[1];
        pp[0][2] = off[2] + row[2];
    }
    #pragma unroll
    for (int s = 1; s <= 12; ++s) {
        const int i  = OFF_IDX[s];
        const int pa = PAR[s];
        const int col = 3*i + 3;                 // in [6,47]
        float L[9];
        rodrigues(row[col], row[col+1], row[col+2], L);
        const float o0 = off[3*i], o1 = off[3*i+1], o2 = off[3*i+2];  // uniform
        #pragma unroll
        for (int c = 0; c < 3; ++c)
            pp[s][c] = o0*ang[pa][c] + o1*ang[pa][3+c] + o2*ang[pa][6+c] + pp[pa][c];
        #pragma unroll
        for (int j = 0; j < 3; ++j)
            #pragma unroll
            for (int kk = 0; kk < 3; ++kk)
                ang[s][3*j+kk] = L[3*j+0]*ang[pa][0+kk]
                               + L[3*j+1]*ang[pa][3+kk]
                               + L[3*j+2]*ang[pa][6+kk];
    }
    __syncthreads();                             // all chunk-A reads done (wave-local)

    // ---- stage chunk B: buf[49r+c] = x[99r+48+c] (overwrites, safe post-barrier) ----
    #pragma unroll
    for (int g = 0; g < 16; ++g)
        #pragma unroll
        for (int u = 0; u < 3; ++u)
            buf[196 * g + lb[u]] = xb[396 * g + gb[u] + CHW];
    __syncthreads();

    // ---- compute slots 13..25 from chunk B (cols 0..45) ----
    #pragma unroll
    for (int s = 13; s < NJ; ++s) {
        const int i  = OFF_IDX[s];
        const int pa = PAR[s];
        const int col = 3*i + 3 - CHW;           // in [0,45]
        float L[9];
        rodrigues(row[col], row[col+1], row[col+2], L);
        const float o0 = off[3*i], o1 = off[3*i+1], o2 = off[3*i+2];
        #pragma unroll
        for (int c = 0; c < 3; ++c)
            pp[s][c] = o0*ang[pa][c] + o1*ang[pa][3+c] + o2*ang[pa][6+c] + pp[pa][c];
        #pragma unroll
        for (int j = 0; j < 3; ++j)
            #pragma unroll
            for (int kk = 0; kk < 3; ++kk)
                ang[s][3*j+kk] = L[3*j+0]*ang[pa][0+kk]
                               + L[3*j+1]*ang[pa][3+kk]
                               + L[3*j+2]*ang[pa][6+kk];
    }
    __syncthreads();                             // buf fully dead -> pack scratch

    // ---- pack pos at stride 78 (fits: 4992 <= 3136? NO — use first 4992 of...) ----
    // buf has 3136 floats; packed needs 4992. Pack in TWO 32-row groups instead:
    // group g2 packs rows [32g2,32g2+32) at stride 78 (2496 floats <= 3136) and
    // flushes linearly — full 64B lines, single touch (R7/R17-proven pattern).
    float* ob = out + (long long)row0 * OUTW;
    #pragma unroll
    for (int g2 = 0; g2 < 2; ++g2) {
        if (g2) __syncthreads();                 // group-0 flush reads done
        if ((l >> 5) == g2) {
            float2* wr2 = reinterpret_cast<float2*>(buf) + 39 * (l & 31);
            #pragma unroll
            for (int j = 0; j < 39; ++j) {
                float2 v;
                v.x = pp[(2*j)   / 3][(2*j)   % 3];   // compile-time indices
                v.y = pp[(2*j+1) / 3][(2*j+1) % 3];
                wr2[j] = v;
            }
        }
        __syncthreads();
        // linear flush of 2496 floats = 624 float4: 624 = 9*64 + 48
        float4* ob4 = reinterpret_cast<float4*>(ob + g2 * (32 * OUTW));
        const float4* b4 = reinterpret_cast<const float4*>(buf);
        #pragma unroll
        for (int j = 0; j < 9; ++j)
            ob4[l + 64*j] = b4[l + 64*j];
        if (l < 48) ob4[l + 576] = b4[l + 576];
    }
}

extern "C" void kernel_launch(void* const* d_in, const int* in_sizes, int n_in,
                              void* d_out, int out_size, void* d_ws, size_t ws_size,
                              hipStream_t stream) {
    const float* x   = (const float*)d_in[0];
    const float* off = (const float*)d_in[1];
    float* out = (float*)d_out;
    const int B = in_sizes[0] / XDIM;      // 262144
    const int grid = B / RPW;              // 4096
    skel_fk<<<grid, TPB, 0, stream>>>(x, off, out);
}

// Round 20
// 37.757 us; speedup vs baseline: 3.6161x; 3.6161x over previous
//
#include <hip/hip_runtime.h>

#define TPB  128     // 2 waves share one 64-row slab via FK branch-parallelism
#define RPW  64      // rows per block, one per lane (per wave)
#define XDIM 99
#define NJ   26
#define OUTW 78

// slot tables (slot 0 = hip, slots 1..25 follow ORDER)
constexpr int OFF_IDX[NJ] = {0,1,2,3,4,6,7,8,9,11,12,13,14,15,16,17,18,19,20,22,24,25,26,27,28,30};
constexpr int PAR[NJ]     = {-1,0,1,2,3,0,5,6,7,0,9,10,11,12,10,14,15,16,17,17,10,20,21,22,23,23};

__device__ __forceinline__ float fast_rcp(float a)  { return __builtin_amdgcn_rcpf(a); }
__device__ __forceinline__ float fast_sqrt(float a) { return __builtin_amdgcn_sqrtf(a); }

__device__ __forceinline__ void rodrigues(float ax, float ay, float az, float* R) {
    const float EPS = 1.1920928955078125e-07f;   // np.finfo(np.float32).eps
    float t = fast_sqrt(ax*ax + ay*ay + az*az);
    float inv = fast_rcp(t + EPS);
    float r0 = ax*inv, r1 = ay*inv, r2 = az*inv;
    float s, c;
    __sincosf(t, &s, &c);
    float omc = 1.0f - c;
    float r00 = r0*r0, r11 = r1*r1, r22 = r2*r2;
    float r01 = r0*r1, r02 = r0*r2, r12 = r1*r2;
    R[0] = 1.0f - omc*(r11 + r22);
    R[1] = -s*r2 + omc*r01;
    R[2] =  s*r1 + omc*r02;
    R[3] =  s*r2 + omc*r01;
    R[4] = 1.0f - omc*(r00 + r22);
    R[5] = -s*r0 + omc*r12;
    R[6] = -s*r1 + omc*r02;
    R[7] =  s*r0 + omc*r12;
    R[8] = 1.0f - omc*(r00 + r11);
}

// one FK chain step; s is always a constant-folded unrolled index
#define STEP(s) do {                                                          \
    const int i_  = OFF_IDX[(s)];                                             \
    const int pa_ = PAR[(s)];                                                 \
    float L[9];                                                               \
    rodrigues(row[3*i_+3], row[3*i_+4], row[3*i_+5], L);                      \
    const float o0 = off[3*i_], o1 = off[3*i_+1], o2 = off[3*i_+2];           \
    _Pragma("unroll")                                                         \
    for (int c = 0; c < 3; ++c)                                               \
        pp[(s)][c] = o0*ang[pa_][c] + o1*ang[pa_][3+c] + o2*ang[pa_][6+c]     \
                   + pp[pa_][c];                                              \
    _Pragma("unroll")                                                         \
    for (int j = 0; j < 3; ++j)                                               \
        _Pragma("unroll")                                                     \
        for (int kk = 0; kk < 3; ++kk)                                        \
            ang[(s)][3*j+kk] = L[3*j+0]*ang[pa_][0+kk]                        \
                             + L[3*j+1]*ang[pa_][3+kk]                        \
                             + L[3*j+2]*ang[pa_][6+kk];                       \
} while (0)

// (128,3): VGPR cap ~170 (paths need ~110-130; headroom against spill cliff).
// LDS 25344B -> 6 blocks/CU x 2 waves = 12 waves/CU = 3/SIMD.
__global__ __launch_bounds__(TPB, 3) void skel_fk(const float* __restrict__ x,
                                                  const float* __restrict__ off,
                                                  float* __restrict__ out) {
    __shared__ __align__(16) float buf[RPW * XDIM];   // 25344 B, shared by both waves
    const int t = threadIdx.x;
    const int w = t >> 6;                        // wave id (uniform branch selector)
    const int l = t & 63;                        // lane = row
    const int row0 = blockIdx.x * RPW;
    const float* gsrc = x + (long long)row0 * XDIM;

    // ---- linear DMA (R17-proven), split between the waves ----
    if (w == 0) {
        #pragma unroll
        for (int j = 0; j < 12; ++j)
            __builtin_amdgcn_global_load_lds(
                (const __attribute__((address_space(1))) unsigned int*)(gsrc + 256*j + 4*l),
                (__attribute__((address_space(3))) unsigned int*)(buf + 256*j),
                16, 0, 0);
        __builtin_amdgcn_global_load_lds(
            (const __attribute__((address_space(1))) unsigned int*)(gsrc + 6144 + l),
            (__attribute__((address_space(3))) unsigned int*)(buf + 6144),
            4, 0, 0);
    } else {
        #pragma unroll
        for (int j = 12; j < 24; ++j)
            __builtin_amdgcn_global_load_lds(
                (const __attribute__((address_space(1))) unsigned int*)(gsrc + 256*j + 4*l),
                (__attribute__((address_space(3))) unsigned int*)(buf + 256*j),
                16, 0, 0);
        #pragma unroll
        for (int kk = 1; kk < 3; ++kk)
            __builtin_amdgcn_global_load_lds(
                (const __attribute__((address_space(1))) unsigned int*)(gsrc + 6144 + 64*kk + l),
                (__attribute__((address_space(3))) unsigned int*)(buf + 6144 + 64*kk),
                4, 0, 0);
    }
    __syncthreads();                             // both waves' DMA drained & visible

    const float* row = &buf[l * XDIM];           // stride 99 -> conflict-free
    float ang[NJ][9];                            // only this wave's slots get touched
    float pp[NJ][3];                             // -> SSA kills the rest

    // hip (both waves need the trunk root)
    {
        float R[9];
        rodrigues(row[3], row[4], row[5], R);
        #pragma unroll
        for (int q = 0; q < 9; ++q) ang[0][q] = R[q];
        pp[0][0] = off[0] + row[0];
        pp[0][1] = off[1] + row[1];
        pp[0][2] = off[2] + row[2];
    }

    if (w == 0) {
        // trunk + legs + head: slots 1..13 (writes out cols [0,42))
        #pragma unroll
        for (int s = 1; s <= 13; ++s) STEP(s);
    } else {
        // redundant trunk {9,10}, then both arms: slots 14..25 (cols [42,78))
        STEP(9);
        STEP(10);
        #pragma unroll
        for (int s = 14; s < NJ; ++s) STEP(s);
    }
    __syncthreads();                             // all slab reads done in both waves

    // ---- pack pos into dead slab at stride 78; wave-disjoint column ranges.
    //      float2 banks: (39l + const) % 32, 39%32=7 coprime -> conflict-free ----
    {
        float2* p2 = reinterpret_cast<float2*>(buf);
        if (w == 0) {
            float2* wr2 = p2 + 39 * l;           // cols [0,42): 21 float2
            #pragma unroll
            for (int j = 0; j < 21; ++j) {
                float2 v;
                v.x = pp[(2*j)   / 3][(2*j)   % 3];   // compile-time indices
                v.y = pp[(2*j+1) / 3][(2*j+1) % 3];
                wr2[j] = v;
            }
        } else {
            float2* wr2 = p2 + 39 * l + 21;      // cols [42,78): 18 float2
            #pragma unroll
            for (int j = 0; j < 18; ++j) {
                const int f = 42 + 2*j;
                float2 v;
                v.x = pp[f / 3][f % 3];
                v.y = pp[(f+1) / 3][(f+1) % 3];
                wr2[j] = v;
            }
        }
    }
    __syncthreads();                             // packed slab visible to all 128

    // ---- flush: pure linear copy, 1248 float4, full 64B lines, single touch ----
    {
        float4* ob4 = reinterpret_cast<float4*>(out + (long long)row0 * OUTW);
        const float4* b4 = reinterpret_cast<const float4*>(buf);
        #pragma unroll
        for (int j = 0; j < 9; ++j)              // 9*128 = 1152
            ob4[t + 128*j] = b4[t + 128*j];
        if (t < 96) ob4[1152 + t] = b4[1152 + t];
    }
}

extern "C" void kernel_launch(void* const* d_in, const int* in_sizes, int n_in,
                              void* d_out, int out_size, void* d_ws, size_t ws_size,
                              hipStream_t stream) {
    const float* x   = (const float*)d_in[0];
    const float* off = (const float*)d_in[1];
    float* out = (float*)d_out;
    const int B = in_sizes[0] / XDIM;      // 262144
    const int grid = B / RPW;              // 4096
    skel_fk<<<grid, TPB, 0, stream>>>(x, off, out);
}

// Round 21
// 36.766 us; speedup vs baseline: 3.7136x; 1.0270x over previous
//
#include <hip/hip_runtime.h>

#define TPB  256     // 4 waves share one 64-row slab via 4-branch FK parallelism
#define RPW  64      // rows per block, one per lane (per wave)
#define XDIM 99
#define NJ   26
#define OUTW 78

// slot tables (slot 0 = hip, slots 1..25 follow ORDER)
constexpr int OFF_IDX[NJ] = {0,1,2,3,4,6,7,8,9,11,12,13,14,15,16,17,18,19,20,22,24,25,26,27,28,30};
constexpr int PAR[NJ]     = {-1,0,1,2,3,0,5,6,7,0,9,10,11,12,10,14,15,16,17,17,10,20,21,22,23,23};

__device__ __forceinline__ float fast_rcp(float a)  { return __builtin_amdgcn_rcpf(a); }
__device__ __forceinline__ float fast_sqrt(float a) { return __builtin_amdgcn_sqrtf(a); }

__device__ __forceinline__ void rodrigues(float ax, float ay, float az, float* R) {
    const float EPS = 1.1920928955078125e-07f;   // np.finfo(np.float32).eps
    float t = fast_sqrt(ax*ax + ay*ay + az*az);
    float inv = fast_rcp(t + EPS);
    float r0 = ax*inv, r1 = ay*inv, r2 = az*inv;
    float s, c;
    __sincosf(t, &s, &c);
    float omc = 1.0f - c;
    float r00 = r0*r0, r11 = r1*r1, r22 = r2*r2;
    float r01 = r0*r1, r02 = r0*r2, r12 = r1*r2;
    R[0] = 1.0f - omc*(r11 + r22);
    R[1] = -s*r2 + omc*r01;
    R[2] =  s*r1 + omc*r02;
    R[3] =  s*r2 + omc*r01;
    R[4] = 1.0f - omc*(r00 + r22);
    R[5] = -s*r0 + omc*r12;
    R[6] = -s*r1 + omc*r02;
    R[7] =  s*r0 + omc*r12;
    R[8] = 1.0f - omc*(r00 + r11);
}

// one FK chain step; s is always a constant unrolled index
#define STEP(s) do {                                                          \
    const int i_  = OFF_IDX[(s)];                                             \
    const int pa_ = PAR[(s)];                                                 \
    float L[9];                                                               \
    rodrigues(row[3*i_+3], row[3*i_+4], row[3*i_+5], L);                      \
    const float o0 = off[3*i_], o1 = off[3*i_+1], o2 = off[3*i_+2];           \
    _Pragma("unroll")                                                         \
    for (int c = 0; c < 3; ++c)                                               \
        pp[(s)][c] = o0*ang[pa_][c] + o1*ang[pa_][3+c] + o2*ang[pa_][6+c]     \
                   + pp[pa_][c];                                              \
    _Pragma("unroll")                                                         \
    for (int j = 0; j < 3; ++j)                                               \
        _Pragma("unroll")                                                     \
        for (int kk = 0; kk < 3; ++kk)                                        \
            ang[(s)][3*j+kk] = L[3*j+0]*ang[pa_][0+kk]                        \
                             + L[3*j+1]*ang[pa_][3+kk]                        \
                             + L[3*j+2]*ang[pa_][6+kk];                       \
} while (0)

// (256,4): VGPR cap 128 (R20's longer path measured 76; these are shorter).
// LDS 25344B -> 6 blocks/CU x 4 waves = 24 waves/CU = 6/SIMD if VGPR <= 85.
__global__ __launch_bounds__(TPB, 4) void skel_fk(const float* __restrict__ x,
                                                  const float* __restrict__ off,
                                                  float* __restrict__ out) {
    __shared__ __align__(16) float buf[RPW * XDIM];   // 25344 B, shared by 4 waves
    const int t = threadIdx.x;
    const int w = t >> 6;                        // wave id 0..3 (uniform)
    const int l = t & 63;                        // lane = row
    const int row0 = blockIdx.x * RPW;
    const float* gsrc = x + (long long)row0 * XDIM;

    // ---- linear DMA (R17-proven pattern), split 4 ways: 6 x 16B per wave,
    //      plus one 4B tail op for waves 1..3 ----
    #pragma unroll
    for (int j = 0; j < 6; ++j) {
        const int jj = 6 * w + j;
        __builtin_amdgcn_global_load_lds(
            (const __attribute__((address_space(1))) unsigned int*)(gsrc + 256*jj + 4*l),
            (__attribute__((address_space(3))) unsigned int*)(buf + 256*jj),
            16, 0, 0);
    }
    if (w >= 1) {
        const int kk = w - 1;
        __builtin_amdgcn_global_load_lds(
            (const __attribute__((address_space(1))) unsigned int*)(gsrc + 6144 + 64*kk + l),
            (__attribute__((address_space(3))) unsigned int*)(buf + 6144 + 64*kk),
            4, 0, 0);
    }
    __syncthreads();                             // all DMA drained & visible

    const float* row = &buf[l * XDIM];           // stride 99 -> conflict-free
    float ang[NJ][9];                            // only this wave's slots touched
    float pp[NJ][3];                             // -> SSA reclaims the rest

    // hip (trunk root, all waves)
    {
        float R[9];
        rodrigues(row[3], row[4], row[5], R);
        #pragma unroll
        for (int q = 0; q < 9; ++q) ang[0][q] = R[q];
        pp[0][0] = off[0] + row[0];
        pp[0][1] = off[1] + row[1];
        pp[0][2] = off[2] + row[2];
    }

    if (w == 0) {                                // both legs: slots 1..8
        #pragma unroll
        for (int s = 1; s <= 8; ++s) STEP(s);
    } else if (w == 1) {                         // spine+head: slots 9..13
        #pragma unroll
        for (int s = 9; s <= 13; ++s) STEP(s);
    } else if (w == 2) {                         // left arm: 9,10 (redundant) + 14..19
        STEP(9); STEP(10);
        #pragma unroll
        for (int s = 14; s <= 19; ++s) STEP(s);
    } else {                                     // right arm: 9,10 (redundant) + 20..25
        STEP(9); STEP(10);
        #pragma unroll
        for (int s = 20; s <= 25; ++s) STEP(s);
    }
    __syncthreads();                             // all slab reads done in all waves

    // ---- pack pos into dead slab at stride 78; wave-disjoint column ranges.
    //      scalar ds_writes; lane-stride 78 -> worst 4-way alias on ~24 ops ----
    {
        float* srow = &buf[l * OUTW];            // NOTE: overlays rows compactly
        if (w == 0) {                            // slots 1..8 -> cols [3,27)
            #pragma unroll
            for (int s = 1; s <= 8; ++s) {
                srow[3*s+0] = pp[s][0]; srow[3*s+1] = pp[s][1]; srow[3*s+2] = pp[s][2];
            }
        } else if (w == 1) {                     // slot 0 + 9..13 -> [0,3)+[27,42)
            srow[0] = pp[0][0]; srow[1] = pp[0][1]; srow[2] = pp[0][2];
            #pragma unroll
            for (int s = 9; s <= 13; ++s) {
                srow[3*s+0] = pp[s][0]; srow[3*s+1] = pp[s][1]; srow[3*s+2] = pp[s][2];
            }
        } else if (w == 2) {                     // slots 14..19 -> [42,60)
            #pragma unroll
            for (int s = 14; s <= 19; ++s) {
                srow[3*s+0] = pp[s][0]; srow[3*s+1] = pp[s][1]; srow[3*s+2] = pp[s][2];
            }
        } else {                                 // slots 20..25 -> [60,78)
            #pragma unroll
            for (int s = 20; s <= 25; ++s) {
                srow[3*s+0] = pp[s][0]; srow[3*s+1] = pp[s][1]; srow[3*s+2] = pp[s][2];
            }
        }
    }
    __syncthreads();                             // packed slab visible to all 256

    // ---- flush: pure linear copy, 1248 float4, full 64B lines, single touch ----
    {
        float4* ob4 = reinterpret_cast<float4*>(out + (long long)row0 * OUTW);
        const float4* b4 = reinterpret_cast<const float4*>(buf);
        #pragma unroll
        for (int j = 0; j < 4; ++j)              // 4*256 = 1024
            ob4[t + 256*j] = b4[t + 256*j];
        if (t < 224) ob4[1024 + t] = b4[1024 + t];
    }
}

extern "C" void kernel_launch(void* const* d_in, const int* in_sizes, int n_in,
                              void* d_out, int out_size, void* d_ws, size_t ws_size,
                              hipStream_t stream) {
    const float* x   = (const float*)d_in[0];
    const float* off = (const float*)d_in[1];
    float* out = (float*)d_out;
    const int B = in_sizes[0] / XDIM;      // 262144
    const int grid = B / RPW;              // 4096
    skel_fk<<<grid, TPB, 0, stream>>>(x, off, out);
}